// Round 1
// baseline (9875.060 us; speedup 1.0000x reference)
//
#include <hip/hip_runtime.h>
#include <hip/hip_bf16.h>
#include <math.h>

// Problem constants (QwenAttention: B=2,S=2048,E=2048,H=16,KV=4,D=128)
#define BB 2
#define SS 2048
#define EE 2048
#define HH 16
#define KVH 4
#define GG 4
#define DD 128

// ---------------------------------------------------------------------------
// Tiled fp32 GEMM: C[M,N] = A[M,K] @ W[N,K]^T + bias[N]
// 64x64 tile, BK=16, 256 threads, 4x4 micro-tile per thread.
// ---------------------------------------------------------------------------
#define TILE 64
#define BK 16
__global__ __launch_bounds__(256) void gemm_bias_kernel(
    const float* __restrict__ A, const float* __restrict__ W,
    const float* __restrict__ bias, float* __restrict__ C,
    int M, int N, int K)
{
    __shared__ float As[BK][TILE + 1];
    __shared__ float Bs[BK][TILE + 1];
    int tid = threadIdx.x;
    int tx = tid & 15, ty = tid >> 4;
    int m0 = blockIdx.y * TILE, n0 = blockIdx.x * TILE;
    float acc[4][4] = {};

    for (int k0 = 0; k0 < K; k0 += BK) {
#pragma unroll
        for (int i = 0; i < 4; i++) {
            int idx = tid + i * 256;
            int r = idx >> 4, kk = idx & 15;
            As[kk][r] = A[(size_t)(m0 + r) * K + k0 + kk];
            Bs[kk][r] = W[(size_t)(n0 + r) * K + k0 + kk];
        }
        __syncthreads();
#pragma unroll
        for (int kk = 0; kk < BK; kk++) {
            float a[4], b[4];
#pragma unroll
            for (int i = 0; i < 4; i++) a[i] = As[kk][ty * 4 + i];
#pragma unroll
            for (int j = 0; j < 4; j++) b[j] = Bs[kk][tx * 4 + j];
#pragma unroll
            for (int i = 0; i < 4; i++)
#pragma unroll
                for (int j = 0; j < 4; j++)
                    acc[i][j] = fmaf(a[i], b[j], acc[i][j]);
        }
        __syncthreads();
    }

#pragma unroll
    for (int i = 0; i < 4; i++) {
        int m = m0 + ty * 4 + i;
#pragma unroll
        for (int j = 0; j < 4; j++) {
            int n = n0 + tx * 4 + j;
            float b = bias ? bias[n] : 0.0f;
            C[(size_t)m * N + n] = acc[i][j] + b;
        }
    }
}

// ---------------------------------------------------------------------------
// RoPE (half-rotation layout: rot = concat(-t[64:], t[:64])).
// cos/sin index d and d+64 share the same frequency (emb = concat(freqs,freqs)).
// One block (64 threads) per head-row; thread d handles elements d and d+64.
// ---------------------------------------------------------------------------
__global__ __launch_bounds__(64) void rope_kernel(float* __restrict__ t, int nh)
{
    int row = blockIdx.x;            // (b*S + s)*nh + h
    int s = (row / nh) % SS;
    int d = threadIdx.x;             // 0..63
    float* p = t + (size_t)row * DD;
    // inv_freq[d] = 10000^(-d/64)
    float inv_freq = expf(-(float)d * (logf(10000.0f) / 64.0f));
    float fr = (float)s * inv_freq;
    float c = cosf(fr), sn = sinf(fr);
    float x1 = p[d], x2 = p[d + 64];
    p[d]      = x1 * c - x2 * sn;
    p[d + 64] = x2 * c + x1 * sn;
}

// ---------------------------------------------------------------------------
// Causal GQA attention, one block (256 threads) per query row (b,h,s).
// Scores row lives in LDS (<= 2048 floats); two-pass softmax; PV with
// coalesced V reads (lane -> d).
// q/o layout: [B,S,H,D]; k/v layout: [B,S,KV,D].
// ---------------------------------------------------------------------------
__global__ __launch_bounds__(256) void attn_kernel(
    const float* __restrict__ q, const float* __restrict__ k,
    const float* __restrict__ v, float* __restrict__ o)
{
    __shared__ float qs[DD];
    __shared__ float sc[SS];
    __shared__ float red[256];

    int tid = threadIdx.x;
    int idx = blockIdx.x;            // (b*H + h)*S + s  (s-contig for K/V L2 reuse)
    int s = idx % SS;
    int bh = idx / SS;
    int h = bh % HH;
    int b = bh / HH;
    int kv = h >> 2;                 // G=4

    const float* qp = q + (((size_t)(b * SS + s)) * HH + h) * DD;
    if (tid < DD) qs[tid] = qp[tid];
    __syncthreads();

    const float scale = 0.088388347648318447f;  // 1/sqrt(128)

    // Pass 1: scores
    float mloc = -INFINITY;
    for (int t = tid; t <= s; t += 256) {
        const float4* kr = (const float4*)(k + ((size_t)(b * SS + t) * KVH + kv) * DD);
        const float4* qq = (const float4*)qs;
        float dot = 0.0f;
#pragma unroll
        for (int i = 0; i < DD / 4; i++) {
            float4 kk4 = kr[i];
            float4 q4 = qq[i];
            dot += q4.x * kk4.x + q4.y * kk4.y + q4.z * kk4.z + q4.w * kk4.w;
        }
        float sv = dot * scale;
        sc[t] = sv;
        mloc = fmaxf(mloc, sv);
    }

    // Reduce max
    red[tid] = mloc;
    __syncthreads();
    for (int off = 128; off > 0; off >>= 1) {
        if (tid < off) red[tid] = fmaxf(red[tid], red[tid + off]);
        __syncthreads();
    }
    float m = red[0];
    __syncthreads();

    // Pass 2: exp + sum
    float lsum = 0.0f;
    for (int t = tid; t <= s; t += 256) {
        float p = expf(sc[t] - m);
        sc[t] = p;
        lsum += p;
    }
    red[tid] = lsum;
    __syncthreads();
    for (int off = 128; off > 0; off >>= 1) {
        if (tid < off) red[tid] += red[tid + off];
        __syncthreads();
    }
    float l = red[0];
    __syncthreads();

    // Pass 3: O = P @ V  (two t-halves per d, combined via LDS)
    int d = tid & (DD - 1);
    int half = tid >> 7;
    float acc = 0.0f;
    for (int t = half; t <= s; t += 2)
        acc += sc[t] * v[((size_t)(b * SS + t) * KVH + kv) * DD + d];
    red[tid] = acc;
    __syncthreads();
    if (half == 0) {
        float val = (red[tid] + red[tid + 128]) / l;
        o[(((size_t)(b * SS + s)) * HH + h) * DD + d] = val;
    }
}

// ---------------------------------------------------------------------------
extern "C" void kernel_launch(void* const* d_in, const int* in_sizes, int n_in,
                              void* d_out, int out_size, void* d_ws, size_t ws_size,
                              hipStream_t stream)
{
    const float* x  = (const float*)d_in[0];
    const float* Wq = (const float*)d_in[1];
    const float* bq = (const float*)d_in[2];
    const float* Wk = (const float*)d_in[3];
    const float* bk = (const float*)d_in[4];
    const float* Wv = (const float*)d_in[5];
    const float* bv = (const float*)d_in[6];
    const float* Wo = (const float*)d_in[7];
    float* out = (float*)d_out;

    const int M = BB * SS;           // 4096
    float* qb = (float*)d_ws;                     // M * H*D   = 8.4M floats
    float* kb = qb + (size_t)M * HH * DD;         // M * KV*D  = 2.1M
    float* vb = kb + (size_t)M * KVH * DD;        // M * KV*D  = 2.1M
    float* ab = vb + (size_t)M * KVH * DD;        // M * H*D   = 8.4M

    dim3 blk(256);

    // QKV projections
    gemm_bias_kernel<<<dim3((HH * DD) / TILE, M / TILE), blk, 0, stream>>>(
        x, Wq, bq, qb, M, HH * DD, EE);
    gemm_bias_kernel<<<dim3((KVH * DD) / TILE, M / TILE), blk, 0, stream>>>(
        x, Wk, bk, kb, M, KVH * DD, EE);
    gemm_bias_kernel<<<dim3((KVH * DD) / TILE, M / TILE), blk, 0, stream>>>(
        x, Wv, bv, vb, M, KVH * DD, EE);

    // RoPE on q and k
    rope_kernel<<<M * HH, 64, 0, stream>>>(qb, HH);
    rope_kernel<<<M * KVH, 64, 0, stream>>>(kb, KVH);

    // Attention
    attn_kernel<<<BB * HH * SS, 256, 0, stream>>>(qb, kb, vb, ab);

    // Output projection (no bias)
    gemm_bias_kernel<<<dim3(EE / TILE, M / TILE), blk, 0, stream>>>(
        ab, Wo, nullptr, out, M, EE, HH * DD);
}

// Round 2
// 2024.133 us; speedup vs baseline: 4.8787x; 4.8787x over previous
//
#include <hip/hip_runtime.h>
#include <hip/hip_bf16.h>
#include <math.h>

// Problem constants (QwenAttention: B=2,S=2048,E=2048,H=16,KV=4,D=128)
#define BB 2
#define SS 2048
#define EE 2048
#define HH 16
#define KVH 4
#define DD 128
#define QTILES 32   // S / 64

typedef short short8 __attribute__((ext_vector_type(8)));
typedef float f32x4 __attribute__((ext_vector_type(4)));

__device__ __forceinline__ unsigned int f2bf1(float x) {
    union { float f; unsigned int u; } v; v.f = x;
    return (v.u + 0x7FFFu + ((v.u >> 16) & 1u)) >> 16;  // RNE bf16
}
__device__ __forceinline__ unsigned int packbf(float a, float b) {
    return f2bf1(a) | (f2bf1(b) << 16);
}

// ---------------------------------------------------------------------------
// Tiled fp32 GEMM: C[M,N] = A[M,K] @ W[N,K]^T + bias[N]  (unchanged)
// ---------------------------------------------------------------------------
#define TILE 64
#define BK 16
__global__ __launch_bounds__(256) void gemm_bias_kernel(
    const float* __restrict__ A, const float* __restrict__ W,
    const float* __restrict__ bias, float* __restrict__ C,
    int M, int N, int K)
{
    __shared__ float As[BK][TILE + 1];
    __shared__ float Bs[BK][TILE + 1];
    int tid = threadIdx.x;
    int tx = tid & 15, ty = tid >> 4;
    int m0 = blockIdx.y * TILE, n0 = blockIdx.x * TILE;
    float acc[4][4] = {};

    for (int k0 = 0; k0 < K; k0 += BK) {
#pragma unroll
        for (int i = 0; i < 4; i++) {
            int idx = tid + i * 256;
            int r = idx >> 4, kk = idx & 15;
            As[kk][r] = A[(size_t)(m0 + r) * K + k0 + kk];
            Bs[kk][r] = W[(size_t)(n0 + r) * K + k0 + kk];
        }
        __syncthreads();
#pragma unroll
        for (int kk = 0; kk < BK; kk++) {
            float a[4], b[4];
#pragma unroll
            for (int i = 0; i < 4; i++) a[i] = As[kk][ty * 4 + i];
#pragma unroll
            for (int j = 0; j < 4; j++) b[j] = Bs[kk][tx * 4 + j];
#pragma unroll
            for (int i = 0; i < 4; i++)
#pragma unroll
                for (int j = 0; j < 4; j++)
                    acc[i][j] = fmaf(a[i], b[j], acc[i][j]);
        }
        __syncthreads();
    }

#pragma unroll
    for (int i = 0; i < 4; i++) {
        int m = m0 + ty * 4 + i;
#pragma unroll
        for (int j = 0; j < 4; j++) {
            int n = n0 + tx * 4 + j;
            float b = bias ? bias[n] : 0.0f;
            C[(size_t)m * N + n] = acc[i][j] + b;
        }
    }
}

// ---------------------------------------------------------------------------
// RoPE (unchanged)
// ---------------------------------------------------------------------------
__global__ __launch_bounds__(64) void rope_kernel(float* __restrict__ t, int nh)
{
    int row = blockIdx.x;
    int s = (row / nh) % SS;
    int d = threadIdx.x;
    float* p = t + (size_t)row * DD;
    float inv_freq = expf(-(float)d * (logf(10000.0f) / 64.0f));
    float fr = (float)s * inv_freq;
    float c = cosf(fr), sn = sinf(fr);
    float x1 = p[d], x2 = p[d + 64];
    p[d]      = x1 * c - x2 * sn;
    p[d + 64] = x2 * c + x1 * sn;
}

// ---------------------------------------------------------------------------
// Flash attention, bf16 MFMA 16x16x32.
// Block = 256 threads = 4 waves; wave w owns Q rows [q0+16w, q0+16w+16).
// Each block processes the q-tile PAIR {j, 31-j} -> exactly 33 K-tiles/block.
// Layouts (HW-verified, learn_hip m89/m120):
//   A-frag:  A[m=lane&15][k=quad*8+j],  C/D: row=quad*4+reg, col=lane&15.
// LDS: K row-major [pos][d] bf16-pairs, row stride 68 uints (pad -> b128 reads
//      conflict-free); V transposed [d][pos] bf16-pairs, row stride 36 uints;
//      P per-wave [16][72] shorts (pad).
// ---------------------------------------------------------------------------
__global__ __launch_bounds__(256, 2) void attn_mfma_kernel(
    const float* __restrict__ q, const float* __restrict__ k,
    const float* __restrict__ v, float* __restrict__ o)
{
    __shared__ unsigned int Ks_u[64 * 68];    // 17408 B
    __shared__ unsigned int Vs_u[128 * 36];   // 18432 B
    __shared__ short Ps[4][16 * 72];          //  9216 B

    const int tid  = threadIdx.x;
    const int w    = tid >> 6;
    const int lane = tid & 63;
    const int quad = lane >> 4;
    const int l16  = lane & 15;
    const int jpair = blockIdx.x;   // 0..15
    const int h     = blockIdx.y;
    const int b     = blockIdx.z;
    const int kv    = h >> 2;       // G = 4

    const float scale = 0.08838834764831845f;  // 1/sqrt(128)
    const float* kbase = k + ((size_t)b * SS * KVH + kv) * DD;
    const float* vbase = v + ((size_t)b * SS * KVH + kv) * DD;
    const int RS = KVH * DD;  // 512 floats per position row

    for (int pass = 0; pass < 2; ++pass) {
        const int qt = pass ? (QTILES - 1 - jpair) : jpair;
        const int q0 = qt * 64;

        // ---- Load Q A-frags (scaled by 1/sqrt(D)) ----
        short8 qf[4];
        {
            const int sq = q0 + w * 16 + l16;
            const float* qp = q + (((size_t)(b * SS + sq)) * HH + h) * DD + quad * 8;
#pragma unroll
            for (int ks = 0; ks < 4; ++ks) {
                float4 f0 = *(const float4*)(qp + ks * 32);
                float4 f1 = *(const float4*)(qp + ks * 32 + 4);
                union { short8 s; unsigned int u[4]; } t;
                t.u[0] = packbf(f0.x * scale, f0.y * scale);
                t.u[1] = packbf(f0.z * scale, f0.w * scale);
                t.u[2] = packbf(f1.x * scale, f1.y * scale);
                t.u[3] = packbf(f1.z * scale, f1.w * scale);
                qf[ks] = t.s;
            }
        }

        float m_r[4], l_r[4];
        f32x4 Oacc[8];
#pragma unroll
        for (int r = 0; r < 4; ++r) { m_r[r] = -1e30f; l_r[r] = 0.0f; }
#pragma unroll
        for (int ot = 0; ot < 8; ++ot) Oacc[ot] = (f32x4){0.f, 0.f, 0.f, 0.f};

        for (int t = 0; t <= qt; ++t) {
            const int p0 = t * 64;

            // ---- Stage K tile: Ks[pos][d] bf16 pairs, stride 68 uints ----
            {
                const int c = tid & 31;             // uint-pair col; d = c*4
                const int pb = tid >> 5;            // pos base 0..7
                const float* kp = kbase + (size_t)(p0 + pb) * RS + c * 4;
#pragma unroll
                for (int rr = 0; rr < 8; ++rr) {
                    float4 kd = *(const float4*)(kp + (size_t)rr * 8 * RS);
                    *(uint2*)(&Ks_u[(pb + rr * 8) * 68 + c * 2]) =
                        make_uint2(packbf(kd.x, kd.y), packbf(kd.z, kd.w));
                }
            }
            // ---- Stage V tile transposed: Vs[d][pos] bf16 pairs, stride 36 ----
            {
                const int pp = tid >> 3;            // pos-pair 0..31
                const int dseg = (tid & 7) * 16;
                const float* va = vbase + (size_t)(p0 + 2 * pp) * RS + dseg;
                const float* vb2 = va + RS;
#pragma unroll
                for (int i = 0; i < 4; ++i) {
                    float4 fa = *(const float4*)(va + 4 * i);
                    float4 fb = *(const float4*)(vb2 + 4 * i);
                    Vs_u[(dseg + 4 * i + 0) * 36 + pp] = packbf(fa.x, fb.x);
                    Vs_u[(dseg + 4 * i + 1) * 36 + pp] = packbf(fa.y, fb.y);
                    Vs_u[(dseg + 4 * i + 2) * 36 + pp] = packbf(fa.z, fb.z);
                    Vs_u[(dseg + 4 * i + 3) * 36 + pp] = packbf(fa.w, fb.w);
                }
            }
            __syncthreads();

            // ---- S = Q * K^T  (64x64 per block, 16x64 per wave) ----
            f32x4 S[4];
#pragma unroll
            for (int ct = 0; ct < 4; ++ct) {
                f32x4 s = (f32x4){0.f, 0.f, 0.f, 0.f};
#pragma unroll
                for (int ks = 0; ks < 4; ++ks) {
                    short8 bf = *(const short8*)(&Ks_u[(ct * 16 + l16) * 68 + ks * 16 + quad * 4]);
                    s = __builtin_amdgcn_mfma_f32_16x16x32_bf16(qf[ks], bf, s, 0, 0, 0);
                }
                S[ct] = s;
            }

            // ---- causal mask (only diagonal tile) ----
            if (t == qt) {
                const int rowloc = w * 16 + quad * 4;
#pragma unroll
                for (int ct = 0; ct < 4; ++ct)
#pragma unroll
                    for (int r = 0; r < 4; ++r)
                        if (ct * 16 + l16 > rowloc + r) S[ct][r] = -1e30f;
            }

            // ---- online softmax (rows r = quad*4+reg, reduce across quad) ----
            float mnew[4];
#pragma unroll
            for (int r = 0; r < 4; ++r) {
                float c0 = fmaxf(fmaxf(S[0][r], S[1][r]), fmaxf(S[2][r], S[3][r]));
                c0 = fmaxf(c0, __shfl_xor(c0, 1));
                c0 = fmaxf(c0, __shfl_xor(c0, 2));
                c0 = fmaxf(c0, __shfl_xor(c0, 4));
                c0 = fmaxf(c0, __shfl_xor(c0, 8));
                mnew[r] = fmaxf(m_r[r], c0);
            }
#pragma unroll
            for (int r = 0; r < 4; ++r) {
                float alpha = __expf(m_r[r] - mnew[r]);
                m_r[r] = mnew[r];
                float rs = 0.0f;
#pragma unroll
                for (int ct = 0; ct < 4; ++ct) {
                    float p = __expf(S[ct][r] - mnew[r]);
                    rs += p;
                    Ps[w][(quad * 4 + r) * 72 + ct * 16 + l16] = (short)f2bf1(p);
                }
                rs += __shfl_xor(rs, 1);
                rs += __shfl_xor(rs, 2);
                rs += __shfl_xor(rs, 4);
                rs += __shfl_xor(rs, 8);
                l_r[r] = l_r[r] * alpha + rs;
#pragma unroll
                for (int ot = 0; ot < 8; ++ot) Oacc[ot][r] *= alpha;
            }

            // ---- O += P * V  (P via LDS round-trip into A-layout) ----
            short8 pf0 = *(const short8*)(&Ps[w][l16 * 72 + quad * 8]);
            short8 pf1 = *(const short8*)(&Ps[w][l16 * 72 + 32 + quad * 8]);
#pragma unroll
            for (int ot = 0; ot < 8; ++ot) {
                short8 b0 = *(const short8*)((const short*)&Vs_u[(ot * 16 + l16) * 36 + quad * 4]);
                Oacc[ot] = __builtin_amdgcn_mfma_f32_16x16x32_bf16(pf0, b0, Oacc[ot], 0, 0, 0);
                short8 b1 = *(const short8*)((const short*)&Vs_u[(ot * 16 + l16) * 36 + 16 + quad * 4]);
                Oacc[ot] = __builtin_amdgcn_mfma_f32_16x16x32_bf16(pf1, b1, Oacc[ot], 0, 0, 0);
            }
            __syncthreads();
        }

        // ---- epilogue: O /= l, store fp32 [B,S,H,D] ----
        float inv[4];
#pragma unroll
        for (int r = 0; r < 4; ++r) inv[r] = 1.0f / l_r[r];
        const int orow0 = q0 + w * 16 + quad * 4;
        float* ob = o + (((size_t)(b * SS + orow0)) * HH + h) * DD + l16;
#pragma unroll
        for (int r = 0; r < 4; ++r)
#pragma unroll
            for (int ot = 0; ot < 8; ++ot)
                ob[(size_t)r * (HH * DD) + ot * 16] = Oacc[ot][r] * inv[r];
    }
}

// ---------------------------------------------------------------------------
extern "C" void kernel_launch(void* const* d_in, const int* in_sizes, int n_in,
                              void* d_out, int out_size, void* d_ws, size_t ws_size,
                              hipStream_t stream)
{
    const float* x  = (const float*)d_in[0];
    const float* Wq = (const float*)d_in[1];
    const float* bq = (const float*)d_in[2];
    const float* Wk = (const float*)d_in[3];
    const float* bk = (const float*)d_in[4];
    const float* Wv = (const float*)d_in[5];
    const float* bv = (const float*)d_in[6];
    const float* Wo = (const float*)d_in[7];
    float* out = (float*)d_out;

    const int M = BB * SS;  // 4096
    float* qb = (float*)d_ws;
    float* kb = qb + (size_t)M * HH * DD;
    float* vb = kb + (size_t)M * KVH * DD;
    float* ab = vb + (size_t)M * KVH * DD;

    dim3 blk(256);

    gemm_bias_kernel<<<dim3((HH * DD) / TILE, M / TILE), blk, 0, stream>>>(
        x, Wq, bq, qb, M, HH * DD, EE);
    gemm_bias_kernel<<<dim3((KVH * DD) / TILE, M / TILE), blk, 0, stream>>>(
        x, Wk, bk, kb, M, KVH * DD, EE);
    gemm_bias_kernel<<<dim3((KVH * DD) / TILE, M / TILE), blk, 0, stream>>>(
        x, Wv, bv, vb, M, KVH * DD, EE);

    rope_kernel<<<M * HH, 64, 0, stream>>>(qb, HH);
    rope_kernel<<<M * KVH, 64, 0, stream>>>(kb, KVH);

    // Flash attention: grid = (pair, head, batch)
    attn_mfma_kernel<<<dim3(16, HH, BB), blk, 0, stream>>>(qb, kb, vb, ab);

    gemm_bias_kernel<<<dim3(EE / TILE, M / TILE), blk, 0, stream>>>(
        ab, Wo, nullptr, out, M, EE, HH * DD);
}

// Round 3
// 421.274 us; speedup vs baseline: 23.4409x; 4.8048x over previous
//
#include <hip/hip_runtime.h>
#include <hip/hip_bf16.h>
#include <math.h>

// Problem constants (QwenAttention: B=2,S=2048,E=2048,H=16,KV=4,D=128)
#define BB 2
#define SS 2048
#define EE 2048
#define HH 16
#define KVH 4
#define DD 128
#define QTILES 32   // S / 64

typedef short short8 __attribute__((ext_vector_type(8)));
typedef float f32x4 __attribute__((ext_vector_type(4)));

__device__ __forceinline__ unsigned int f2bf1(float x) {
    union { float f; unsigned int u; } v; v.f = x;
    return (v.u + 0x7FFFu + ((v.u >> 16) & 1u)) >> 16;  // RNE bf16
}
__device__ __forceinline__ unsigned int packbf(float a, float b) {
    return f2bf1(a) | (f2bf1(b) << 16);
}
__device__ __forceinline__ float bf2f(unsigned short u) {
    union { unsigned int u; float f; } v; v.u = ((unsigned int)u) << 16;
    return v.f;
}
// async global->LDS, 16B per lane; LDS dest = wave-uniform base + lane*16
__device__ __forceinline__ void gl_lds16(const void* g, void* l) {
    __builtin_amdgcn_global_load_lds(
        (const __attribute__((address_space(1))) unsigned int*)g,
        (__attribute__((address_space(3))) unsigned int*)l,
        16, 0, 0);
}

// ---------------------------------------------------------------------------
// fp32 -> bf16 conversion (vectorized, n % 4 == 0)
// ---------------------------------------------------------------------------
__global__ __launch_bounds__(256) void cvt_bf16_kernel(
    const float* __restrict__ in, unsigned short* __restrict__ out, int n4)
{
    int i = blockIdx.x * 256 + threadIdx.x;
    if (i < n4) {
        float4 f = ((const float4*)in)[i];
        ((uint2*)out)[i] = make_uint2(packbf(f.x, f.y), packbf(f.z, f.w));
    }
}

__global__ __launch_bounds__(256) void concat_bias_kernel(
    const float* __restrict__ bk, const float* __restrict__ bv, float* __restrict__ bkv)
{
    int i = blockIdx.x * 256 + threadIdx.x;  // grid 4*256 = 1024
    bkv[i] = (i < 512) ? bk[i] : bv[i - 512];
}

// ---------------------------------------------------------------------------
// m97-style bf16 MFMA GEMM: C[M,N] = A[M,K] @ W[N,K]^T + bias[N]
// 128x128 tile, BK=32, 256 threads = 4 waves (2x2), 4x4 MFMA tiles per wave.
// A,W bf16 row-major; global_load_lds width-16 staging (LDS layout unpadded
// row-major [128][32] as required by wave-uniform-base + lane*16 semantics).
// ---------------------------------------------------------------------------
template <bool OUT_BF16>
__global__ __launch_bounds__(256) void gemm_mfma_kernel(
    const unsigned short* __restrict__ A, const unsigned short* __restrict__ W,
    const float* __restrict__ bias, void* __restrict__ Cout,
    int M, int N, int K)
{
    __shared__ unsigned short As[128 * 32];
    __shared__ unsigned short Bs[128 * 32];

    const int tid  = threadIdx.x;
    const int w    = tid >> 6;
    const int lane = tid & 63;
    const int quad = lane >> 4;
    const int l16  = lane & 15;
    const int wr   = w >> 1, wc = w & 1;
    const int m0 = blockIdx.y * 128, n0 = blockIdx.x * 128;

    f32x4 acc[4][4];
#pragma unroll
    for (int i = 0; i < 4; ++i)
#pragma unroll
        for (int j = 0; j < 4; ++j) acc[i][j] = (f32x4){0.f, 0.f, 0.f, 0.f};

    // staging: wave w loads rows [w*32, w*32+32) of both tiles; 4 lanes/row
    const unsigned short* Ag = A + (size_t)(m0 + w * 32 + (lane >> 2)) * K + (lane & 3) * 8;
    const unsigned short* Wg = W + (size_t)(n0 + w * 32 + (lane >> 2)) * K + (lane & 3) * 8;
    unsigned short* AsB = &As[(w * 32) * 32];
    unsigned short* BsB = &Bs[(w * 32) * 32];

    for (int k0 = 0; k0 < K; k0 += 32) {
        gl_lds16(Ag + k0, AsB);
        gl_lds16(Ag + k0 + (size_t)16 * K, AsB + 16 * 32);
        gl_lds16(Wg + k0, BsB);
        gl_lds16(Wg + k0 + (size_t)16 * K, BsB + 16 * 32);
        __syncthreads();

        short8 a_f[4], b_f[4];
#pragma unroll
        for (int i = 0; i < 4; ++i)
            a_f[i] = *(const short8*)&As[(wr * 64 + i * 16 + l16) * 32 + quad * 8];
#pragma unroll
        for (int j = 0; j < 4; ++j)
            b_f[j] = *(const short8*)&Bs[(wc * 64 + j * 16 + l16) * 32 + quad * 8];
#pragma unroll
        for (int i = 0; i < 4; ++i)
#pragma unroll
            for (int j = 0; j < 4; ++j)
                acc[i][j] = __builtin_amdgcn_mfma_f32_16x16x32_bf16(a_f[i], b_f[j], acc[i][j], 0, 0, 0);
        __syncthreads();
    }

    // epilogue: C row = m0 + wr*64 + i*16 + quad*4 + r, col = n0 + wc*64 + j*16 + l16
    float bj[4];
#pragma unroll
    for (int j = 0; j < 4; ++j)
        bj[j] = bias ? bias[n0 + wc * 64 + j * 16 + l16] : 0.0f;
#pragma unroll
    for (int i = 0; i < 4; ++i) {
#pragma unroll
        for (int r = 0; r < 4; ++r) {
            size_t row = m0 + wr * 64 + i * 16 + quad * 4 + r;
#pragma unroll
            for (int j = 0; j < 4; ++j) {
                size_t col = n0 + wc * 64 + j * 16 + l16;
                float val = acc[i][j][r] + bj[j];
                if (OUT_BF16)
                    ((unsigned short*)Cout)[row * N + col] = (unsigned short)f2bf1(val);
                else
                    ((float*)Cout)[row * N + col] = val;
            }
        }
    }
}

// ---------------------------------------------------------------------------
// RoPE on bf16, in place. Block = 64 threads; blockIdx covers (m, head).
// p = t + (m)*rowstride + head*128; thread d handles elems d and d+64.
// ---------------------------------------------------------------------------
__global__ __launch_bounds__(64) void rope_bf16_kernel(
    unsigned short* __restrict__ t, int nh, int rowstride)
{
    int m = blockIdx.x / nh;
    int h = blockIdx.x % nh;
    int s = m % SS;
    int d = threadIdx.x;
    unsigned short* p = t + (size_t)m * rowstride + h * 128;
    float inv_freq = expf(-(float)d * (logf(10000.0f) / 64.0f));
    float fr = (float)s * inv_freq;
    float c = cosf(fr), sn = sinf(fr);
    float x1 = bf2f(p[d]), x2 = bf2f(p[d + 64]);
    p[d]      = (unsigned short)f2bf1(x1 * c - x2 * sn);
    p[d + 64] = (unsigned short)f2bf1(x2 * c + x1 * sn);
}

// ---------------------------------------------------------------------------
// Flash attention, bf16 in / bf16 out, MFMA 16x16x32.
// q: [B*S, 2048] (col = h*128+d); kv: [B*S, 1024] (cols 0..511 K, 512..1023 V).
// Block = 4 waves; block processes q-tile pair {j, 31-j} -> 33 K-tiles each.
// ---------------------------------------------------------------------------
__global__ __launch_bounds__(256, 2) void attn_mfma_kernel(
    const unsigned short* __restrict__ q, const unsigned short* __restrict__ kvb,
    unsigned short* __restrict__ o)
{
    __shared__ unsigned int Ks_u[64 * 68];    // 17408 B
    __shared__ unsigned int Vs_u[128 * 36];   // 18432 B
    __shared__ short Ps[4][16 * 72];          //  9216 B

    const int tid  = threadIdx.x;
    const int w    = tid >> 6;
    const int lane = tid & 63;
    const int quad = lane >> 4;
    const int l16  = lane & 15;
    const int jpair = blockIdx.x;   // 0..15
    const int h     = blockIdx.y;
    const int b     = blockIdx.z;
    const int kv    = h >> 2;       // G = 4

    const float scale = 0.08838834764831845f;  // 1/sqrt(128)
    const unsigned short* kbase = kvb + (size_t)b * SS * 1024 + kv * 128;
    const unsigned short* vbase = kbase + 512;

    for (int pass = 0; pass < 2; ++pass) {
        const int qt = pass ? (QTILES - 1 - jpair) : jpair;
        const int q0 = qt * 64;

        // ---- Q A-frags ----
        short8 qf[4];
        {
            const int sq = q0 + w * 16 + l16;
            const unsigned short* qp = q + (size_t)(b * SS + sq) * 2048 + h * 128 + quad * 8;
#pragma unroll
            for (int ks = 0; ks < 4; ++ks)
                qf[ks] = *(const short8*)(qp + ks * 32);
        }

        float m_r[4], l_r[4];
        f32x4 Oacc[8];
#pragma unroll
        for (int r = 0; r < 4; ++r) { m_r[r] = -1e30f; l_r[r] = 0.0f; }
#pragma unroll
        for (int ot = 0; ot < 8; ++ot) Oacc[ot] = (f32x4){0.f, 0.f, 0.f, 0.f};

        for (int t = 0; t <= qt; ++t) {
            const int p0 = t * 64;

            // ---- Stage K tile: Ks[pos][d], stride 68 uints ----
            {
                const int c  = tid & 15;     // 8-elem chunk
                const int pb = tid >> 4;     // 0..15
#pragma unroll
                for (int rr = 0; rr < 4; ++rr) {
                    int pos = pb + rr * 16;
                    *(uint4*)(&Ks_u[pos * 68 + c * 4]) =
                        *(const uint4*)(kbase + (size_t)(p0 + pos) * 1024 + c * 8);
                }
            }
            // ---- Stage V transposed: Vs[d][pos-pair], stride 36 uints ----
            {
                const int pp   = tid >> 3;         // 0..31 pos pairs
                const int dseg = (tid & 7) * 16;   // 0..112
                const unsigned short* va = vbase + (size_t)(p0 + 2 * pp) * 1024 + dseg;
                uint4 ua0 = *(const uint4*)(va);
                uint4 ua1 = *(const uint4*)(va + 8);
                uint4 ub0 = *(const uint4*)(va + 1024);
                uint4 ub1 = *(const uint4*)(va + 1024 + 8);
#define WR2(i, a, bb2) { \
    Vs_u[(dseg + (i)) * 36 + pp]     = ((a) & 0xffffu) | ((bb2) << 16); \
    Vs_u[(dseg + (i) + 1) * 36 + pp] = ((a) >> 16) | ((bb2) & 0xffff0000u); }
                WR2(0,  ua0.x, ub0.x) WR2(2,  ua0.y, ub0.y)
                WR2(4,  ua0.z, ub0.z) WR2(6,  ua0.w, ub0.w)
                WR2(8,  ua1.x, ub1.x) WR2(10, ua1.y, ub1.y)
                WR2(12, ua1.z, ub1.z) WR2(14, ua1.w, ub1.w)
#undef WR2
            }
            __syncthreads();

            // ---- S = Q @ K^T (16x64 per wave), scale post-MFMA ----
            f32x4 S[4];
#pragma unroll
            for (int ct = 0; ct < 4; ++ct) {
                f32x4 s = (f32x4){0.f, 0.f, 0.f, 0.f};
#pragma unroll
                for (int ks = 0; ks < 4; ++ks) {
                    short8 kf = *(const short8*)(&Ks_u[(ct * 16 + l16) * 68 + ks * 16 + quad * 4]);
                    s = __builtin_amdgcn_mfma_f32_16x16x32_bf16(qf[ks], kf, s, 0, 0, 0);
                }
#pragma unroll
                for (int r = 0; r < 4; ++r) s[r] *= scale;
                S[ct] = s;
            }

            // ---- causal mask (diagonal tile only) ----
            if (t == qt) {
                const int rowloc = w * 16 + quad * 4;
#pragma unroll
                for (int ct = 0; ct < 4; ++ct)
#pragma unroll
                    for (int r = 0; r < 4; ++r)
                        if (ct * 16 + l16 > rowloc + r) S[ct][r] = -1e30f;
            }

            // ---- online softmax ----
            float mnew[4];
#pragma unroll
            for (int r = 0; r < 4; ++r) {
                float c0 = fmaxf(fmaxf(S[0][r], S[1][r]), fmaxf(S[2][r], S[3][r]));
                c0 = fmaxf(c0, __shfl_xor(c0, 1));
                c0 = fmaxf(c0, __shfl_xor(c0, 2));
                c0 = fmaxf(c0, __shfl_xor(c0, 4));
                c0 = fmaxf(c0, __shfl_xor(c0, 8));
                mnew[r] = fmaxf(m_r[r], c0);
            }
#pragma unroll
            for (int r = 0; r < 4; ++r) {
                float alpha = __expf(m_r[r] - mnew[r]);
                m_r[r] = mnew[r];
                float rs = 0.0f;
#pragma unroll
                for (int ct = 0; ct < 4; ++ct) {
                    float p = __expf(S[ct][r] - mnew[r]);
                    rs += p;
                    Ps[w][(quad * 4 + r) * 72 + ct * 16 + l16] = (short)f2bf1(p);
                }
                rs += __shfl_xor(rs, 1);
                rs += __shfl_xor(rs, 2);
                rs += __shfl_xor(rs, 4);
                rs += __shfl_xor(rs, 8);
                l_r[r] = l_r[r] * alpha + rs;
#pragma unroll
                for (int ot = 0; ot < 8; ++ot) Oacc[ot][r] *= alpha;
            }

            // ---- O += P @ V ----
            short8 pf0 = *(const short8*)(&Ps[w][l16 * 72 + quad * 8]);
            short8 pf1 = *(const short8*)(&Ps[w][l16 * 72 + 32 + quad * 8]);
#pragma unroll
            for (int ot = 0; ot < 8; ++ot) {
                short8 b0 = *(const short8*)((const short*)&Vs_u[(ot * 16 + l16) * 36 + quad * 4]);
                Oacc[ot] = __builtin_amdgcn_mfma_f32_16x16x32_bf16(pf0, b0, Oacc[ot], 0, 0, 0);
                short8 b1 = *(const short8*)((const short*)&Vs_u[(ot * 16 + l16) * 36 + 16 + quad * 4]);
                Oacc[ot] = __builtin_amdgcn_mfma_f32_16x16x32_bf16(pf1, b1, Oacc[ot], 0, 0, 0);
            }
            __syncthreads();
        }

        // ---- epilogue: bf16 store ----
        float inv[4];
#pragma unroll
        for (int r = 0; r < 4; ++r) inv[r] = 1.0f / l_r[r];
        const int orow0 = q0 + w * 16 + quad * 4;
        unsigned short* ob = o + (size_t)(b * SS + orow0) * 2048 + h * 128 + l16;
#pragma unroll
        for (int r = 0; r < 4; ++r)
#pragma unroll
            for (int ot = 0; ot < 8; ++ot)
                ob[(size_t)r * 2048 + ot * 16] = (unsigned short)f2bf1(Oacc[ot][r] * inv[r]);
    }
}

// ---------------------------------------------------------------------------
extern "C" void kernel_launch(void* const* d_in, const int* in_sizes, int n_in,
                              void* d_out, int out_size, void* d_ws, size_t ws_size,
                              hipStream_t stream)
{
    const float* x  = (const float*)d_in[0];
    const float* Wq = (const float*)d_in[1];
    const float* bq = (const float*)d_in[2];
    const float* Wk = (const float*)d_in[3];
    const float* bk = (const float*)d_in[4];
    const float* Wv = (const float*)d_in[5];
    const float* bv = (const float*)d_in[6];
    const float* Wo = (const float*)d_in[7];
    float* out = (float*)d_out;

    const int M = BB * SS;  // 4096
    char* wsb = (char*)d_ws;
    unsigned short* xb   = (unsigned short*)wsb;  wsb += (size_t)M * EE * 2;          // 16.8 MB
    unsigned short* wqb  = (unsigned short*)wsb;  wsb += (size_t)EE * EE * 2;         //  8.4 MB
    unsigned short* wkvb = (unsigned short*)wsb;  wsb += (size_t)1024 * EE * 2;       //  4.2 MB
    unsigned short* wob  = (unsigned short*)wsb;  wsb += (size_t)EE * EE * 2;         //  8.4 MB
    unsigned short* qb   = (unsigned short*)wsb;  wsb += (size_t)M * 2048 * 2;        // 16.8 MB
    unsigned short* kvb  = (unsigned short*)wsb;  wsb += (size_t)M * 1024 * 2;        //  8.4 MB
    unsigned short* abb  = (unsigned short*)wsb;  wsb += (size_t)M * 2048 * 2;        // 16.8 MB
    float* bkv = (float*)wsb;

    // fp32 -> bf16 conversions
    cvt_bf16_kernel<<<(M * EE / 4) / 256, 256, 0, stream>>>(x, xb, M * EE / 4);
    cvt_bf16_kernel<<<(EE * EE / 4) / 256, 256, 0, stream>>>(Wq, wqb, EE * EE / 4);
    cvt_bf16_kernel<<<(512 * EE / 4) / 256, 256, 0, stream>>>(Wk, wkvb, 512 * EE / 4);
    cvt_bf16_kernel<<<(512 * EE / 4) / 256, 256, 0, stream>>>(Wv, wkvb + (size_t)512 * EE, 512 * EE / 4);
    cvt_bf16_kernel<<<(EE * EE / 4) / 256, 256, 0, stream>>>(Wo, wob, EE * EE / 4);
    concat_bias_kernel<<<4, 256, 0, stream>>>(bk, bv, bkv);

    // Q projection: [M,2048] = xb @ wqb^T + bq   (bf16 out)
    gemm_mfma_kernel<true><<<dim3(2048 / 128, M / 128), 256, 0, stream>>>(
        xb, wqb, bq, qb, M, 2048, EE);
    // KV projection: [M,1024] = xb @ wkvb^T + bkv (bf16 out; cols 0..511 K, 512..1023 V)
    gemm_mfma_kernel<true><<<dim3(1024 / 128, M / 128), 256, 0, stream>>>(
        xb, wkvb, bkv, kvb, M, 1024, EE);

    // RoPE on q and k (in place, bf16)
    rope_bf16_kernel<<<M * HH, 64, 0, stream>>>(qb, HH, 2048);
    rope_bf16_kernel<<<M * KVH, 64, 0, stream>>>(kvb, KVH, 1024);

    // Flash attention -> abb (bf16)
    attn_mfma_kernel<<<dim3(16, HH, BB), 256, 0, stream>>>(qb, kvb, abb);

    // Output projection: out = abb @ wob^T (fp32 out)
    gemm_mfma_kernel<false><<<dim3(EE / 128, M / 128), 256, 0, stream>>>(
        abb, wob, nullptr, out, M, EE, 2048);
}

// Round 4
// 376.321 us; speedup vs baseline: 26.2410x; 1.1195x over previous
//
#include <hip/hip_runtime.h>
#include <hip/hip_bf16.h>
#include <math.h>

// Problem constants (QwenAttention: B=2,S=2048,E=2048,H=16,KV=4,D=128)
#define BB 2
#define SS 2048
#define EE 2048
#define HH 16
#define KVH 4
#define DD 128
#define QTILES 32   // S / 64

typedef short short8 __attribute__((ext_vector_type(8)));
typedef float f32x4 __attribute__((ext_vector_type(4)));

__device__ __forceinline__ unsigned int f2bf1(float x) {
    union { float f; unsigned int u; } v; v.f = x;
    return (v.u + 0x7FFFu + ((v.u >> 16) & 1u)) >> 16;  // RNE bf16
}
__device__ __forceinline__ unsigned int packbf(float a, float b) {
    return f2bf1(a) | (f2bf1(b) << 16);
}
// async global->LDS, 16B per lane; LDS dest = wave-uniform base + lane*16
__device__ __forceinline__ void gl_lds16(const void* g, void* l) {
    __builtin_amdgcn_global_load_lds(
        (const __attribute__((address_space(1))) unsigned int*)g,
        (__attribute__((address_space(3))) unsigned int*)l,
        16, 0, 0);
}

// ---------------------------------------------------------------------------
// Fused fp32->bf16 conversion of all inputs + bias concat, one launch.
// Segments in float4 units: x | Wq | Wk | Wv | Wo | biases(fp32 copy).
// ---------------------------------------------------------------------------
__global__ __launch_bounds__(256) void cvt_all_kernel(
    const float* __restrict__ x,  const float* __restrict__ Wq,
    const float* __restrict__ Wk, const float* __restrict__ Wv,
    const float* __restrict__ Wo, const float* __restrict__ bq,
    const float* __restrict__ bk, const float* __restrict__ bv,
    unsigned short* __restrict__ xb, unsigned short* __restrict__ wqkv,
    unsigned short* __restrict__ wob, float* __restrict__ bqkv)
{
    long id = (long)blockIdx.x * 256 + threadIdx.x;
    const float* src; unsigned short* dst; long j;
    if (id < 2097152)      { j = id;           src = x;  dst = xb; }
    else if (id < 3145728) { j = id - 2097152; src = Wq; dst = wqkv; }
    else if (id < 3407872) { j = id - 3145728; src = Wk; dst = wqkv + 4194304; }
    else if (id < 3670016) { j = id - 3407872; src = Wv; dst = wqkv + 5242880; }
    else if (id < 4718592) { j = id - 3670016; src = Wo; dst = wob; }
    else if (id < 4719360) {
        long c = (id - 4718592) * 4;
#pragma unroll
        for (int e = 0; e < 4; ++e) {
            long cc = c + e;
            bqkv[cc] = (cc < 2048) ? bq[cc] : (cc < 2560 ? bk[cc - 2048] : bv[cc - 2560]);
        }
        return;
    } else return;
    float4 f = ((const float4*)src)[j];
    ((uint2*)dst)[j] = make_uint2(packbf(f.x, f.y), packbf(f.z, f.w));
}

// ---------------------------------------------------------------------------
// m97-style bf16 MFMA GEMM: C[M,N] = A[M,K] @ W[N,K]^T + bias[N]
// 128x128 tile, BK=32, 256 threads = 4 waves (2x2), 4x4 MFMA tiles per wave.
// ---------------------------------------------------------------------------
template <bool OUT_BF16>
__global__ __launch_bounds__(256) void gemm_mfma_kernel(
    const unsigned short* __restrict__ A, const unsigned short* __restrict__ W,
    const float* __restrict__ bias, void* __restrict__ Cout,
    int M, int N, int K)
{
    __shared__ unsigned short As[128 * 32];
    __shared__ unsigned short Bs[128 * 32];

    const int tid  = threadIdx.x;
    const int w    = tid >> 6;
    const int lane = tid & 63;
    const int quad = lane >> 4;
    const int l16  = lane & 15;
    const int wr   = w >> 1, wc = w & 1;
    const int m0 = blockIdx.y * 128, n0 = blockIdx.x * 128;

    f32x4 acc[4][4];
#pragma unroll
    for (int i = 0; i < 4; ++i)
#pragma unroll
        for (int j = 0; j < 4; ++j) acc[i][j] = (f32x4){0.f, 0.f, 0.f, 0.f};

    const unsigned short* Ag = A + (size_t)(m0 + w * 32 + (lane >> 2)) * K + (lane & 3) * 8;
    const unsigned short* Wg = W + (size_t)(n0 + w * 32 + (lane >> 2)) * K + (lane & 3) * 8;
    unsigned short* AsB = &As[(w * 32) * 32];
    unsigned short* BsB = &Bs[(w * 32) * 32];

    for (int k0 = 0; k0 < K; k0 += 32) {
        gl_lds16(Ag + k0, AsB);
        gl_lds16(Ag + k0 + (size_t)16 * K, AsB + 16 * 32);
        gl_lds16(Wg + k0, BsB);
        gl_lds16(Wg + k0 + (size_t)16 * K, BsB + 16 * 32);
        __syncthreads();

        short8 a_f[4], b_f[4];
#pragma unroll
        for (int i = 0; i < 4; ++i)
            a_f[i] = *(const short8*)&As[(wr * 64 + i * 16 + l16) * 32 + quad * 8];
#pragma unroll
        for (int j = 0; j < 4; ++j)
            b_f[j] = *(const short8*)&Bs[(wc * 64 + j * 16 + l16) * 32 + quad * 8];
#pragma unroll
        for (int i = 0; i < 4; ++i)
#pragma unroll
            for (int j = 0; j < 4; ++j)
                acc[i][j] = __builtin_amdgcn_mfma_f32_16x16x32_bf16(a_f[i], b_f[j], acc[i][j], 0, 0, 0);
        __syncthreads();
    }

    float bj[4];
#pragma unroll
    for (int j = 0; j < 4; ++j)
        bj[j] = bias ? bias[n0 + wc * 64 + j * 16 + l16] : 0.0f;
#pragma unroll
    for (int i = 0; i < 4; ++i) {
#pragma unroll
        for (int r = 0; r < 4; ++r) {
            size_t row = m0 + wr * 64 + i * 16 + quad * 4 + r;
#pragma unroll
            for (int j = 0; j < 4; ++j) {
                size_t col = n0 + wc * 64 + j * 16 + l16;
                float val = acc[i][j][r] + bj[j];
                if (OUT_BF16)
                    ((unsigned short*)Cout)[row * N + col] = (unsigned short)f2bf1(val);
                else
                    ((float*)Cout)[row * N + col] = val;
            }
        }
    }
}

// ---------------------------------------------------------------------------
// RoPE on bf16 qkv buffer [M, 3072] (q cols 0..2047, k cols 2048..2559).
// One launch: blocks [0,65536) -> q heads, [65536,81920) -> k heads.
// ---------------------------------------------------------------------------
__global__ __launch_bounds__(64) void rope_kernel(unsigned short* __restrict__ qkv)
{
    int bix = blockIdx.x;
    int m, col;
    if (bix < 65536) { m = bix >> 4; col = (bix & 15) * 128; }
    else { int i = bix - 65536; m = i >> 2; col = 2048 + (i & 3) * 128; }
    int s = m & (SS - 1);
    int d = threadIdx.x;
    unsigned short* p = qkv + (size_t)m * 3072 + col;
    float inv_freq = expf(-(float)d * (logf(10000.0f) / 64.0f));
    float fr = (float)s * inv_freq;
    float c = cosf(fr), sn = sinf(fr);
    union { unsigned int u; float f; } x1, x2;
    x1.u = ((unsigned int)p[d]) << 16;
    x2.u = ((unsigned int)p[d + 64]) << 16;
    p[d]      = (unsigned short)f2bf1(x1.f * c - x2.f * sn);
    p[d + 64] = (unsigned short)f2bf1(x2.f * c + x1.f * sn);
}

// ---------------------------------------------------------------------------
// Flash attention, bf16, MFMA 16x16x32, XOR-swizzled LDS (conflict-free),
// double-buffered K/V with register prefetch -> ONE barrier per K-tile.
// qkv: [B*S, 3072] (q: h*128, k: 2048+kv*128, v: 2560+kv*128); o: [B*S, 2048].
// Swizzle keys: K/V chunk' = chunk ^ ((row + (row>>4)) & 7) at 16B-chunk
// granularity; P chunk' = chunk ^ ((row>>2) ^ ((row&3)<<1)).
// Verified: staging writes <=2-way (free), all b128 frag reads spread 8
// lanes per 4-bank window (minimum rounds).
// ---------------------------------------------------------------------------
__global__ __launch_bounds__(256, 2) void attn_mfma_kernel(
    const unsigned short* __restrict__ qkv, unsigned short* __restrict__ o)
{
    __shared__ unsigned int Ks_u[2][64 * 64];    // 2 x 16 KB
    __shared__ unsigned int Vs_u[2][128 * 32];   // 2 x 16 KB
    __shared__ unsigned short Ps[4][16 * 64];    // 8 KB, per-wave

    const int tid  = threadIdx.x;
    const int w    = tid >> 6;
    const int lane = tid & 63;
    const int quad = lane >> 4;
    const int l16  = lane & 15;
    const int jpair = blockIdx.x;   // 0..15
    const int h     = blockIdx.y;
    const int b     = blockIdx.z;
    const int kv    = h >> 2;       // G = 4

    const float k2 = 0.12752789744920764f;  // (1/sqrt(128)) * log2(e)

    const unsigned short* kbase = qkv + (size_t)b * SS * 3072 + 2048 + kv * 128;
    const unsigned short* vbase = kbase + 512;

    const int kc  = tid & 15;          // K chunk (8 dims)
    const int kp0 = tid >> 4;          // K row base 0..15
    const int vpp = tid >> 3;          // V pos-pair 0..31
    const int vd0 = (tid & 7) * 16;    // V d-segment base

    for (int pass = 0; pass < 2; ++pass) {
        const int qt = pass ? (QTILES - 1 - jpair) : jpair;
        const int q0 = qt * 64;

        // ---- Q A-frags ----
        short8 qf[4];
        {
            const unsigned short* qp = qkv + (size_t)(b * SS + q0 + w * 16 + l16) * 3072 + h * 128 + quad * 8;
#pragma unroll
            for (int ks = 0; ks < 4; ++ks)
                qf[ks] = *(const short8*)(qp + ks * 32);
        }

        // ---- prefetch tile 0 into regs ----
        uint4 kpre[4], vpa[2], vpb[2];
        {
            const unsigned short* kg = kbase + (size_t)kp0 * 3072 + kc * 8;
#pragma unroll
            for (int rr = 0; rr < 4; ++rr)
                kpre[rr] = *(const uint4*)(kg + (size_t)rr * 16 * 3072);
            const unsigned short* vg = vbase + (size_t)(2 * vpp) * 3072 + vd0;
            vpa[0] = *(const uint4*)(vg);
            vpa[1] = *(const uint4*)(vg + 8);
            vpb[0] = *(const uint4*)(vg + 3072);
            vpb[1] = *(const uint4*)(vg + 3072 + 8);
        }

        float m_r[4], l_r[4];
        f32x4 Oacc[8];
#pragma unroll
        for (int r = 0; r < 4; ++r) { m_r[r] = -1e30f; l_r[r] = 0.0f; }
#pragma unroll
        for (int ot = 0; ot < 8; ++ot) Oacc[ot] = (f32x4){0.f, 0.f, 0.f, 0.f};

        for (int t = 0; t <= qt; ++t) {
            const int buf = t & 1;
            unsigned int* Kb = Ks_u[buf];
            unsigned int* Vb = Vs_u[buf];

            // ---- staged regs -> LDS (swizzled, conflict-free) ----
#pragma unroll
            for (int rr = 0; rr < 4; ++rr) {
                int pos = kp0 + rr * 16;
                int key = (kp0 + rr) & 7;           // (pos + (pos>>4)) & 7
                *(uint4*)&Kb[pos * 64 + (kc ^ key) * 4] = kpre[rr];
            }
            {
                const unsigned int* pa = (const unsigned int*)vpa;
                const unsigned int* pb = (const unsigned int*)vpb;
#pragma unroll
                for (int j = 0; j < 8; ++j) {
                    unsigned lo = __builtin_amdgcn_perm(pb[j], pa[j], 0x05040100);
                    unsigned hi = __builtin_amdgcn_perm(pb[j], pa[j], 0x07060302);
                    int d0 = vd0 + 2 * j;
                    int g  = d0 >> 4;               // same for d0 and d0+1
                    int k0 = (d0 + g) & 7;
                    int k1 = (d0 + 1 + g) & 7;
                    Vb[d0 * 32 + (((vpp >> 2) ^ k0) & 7) * 4 + (vpp & 3)] = lo;
                    Vb[(d0 + 1) * 32 + (((vpp >> 2) ^ k1) & 7) * 4 + (vpp & 3)] = hi;
                }
            }

            // ---- prefetch tile t+1 (latency hidden under compute) ----
            if (t < qt) {
                const unsigned short* kg = kbase + (size_t)((t + 1) * 64 + kp0) * 3072 + kc * 8;
#pragma unroll
                for (int rr = 0; rr < 4; ++rr)
                    kpre[rr] = *(const uint4*)(kg + (size_t)rr * 16 * 3072);
                const unsigned short* vg = vbase + (size_t)((t + 1) * 64 + 2 * vpp) * 3072 + vd0;
                vpa[0] = *(const uint4*)(vg);
                vpa[1] = *(const uint4*)(vg + 8);
                vpb[0] = *(const uint4*)(vg + 3072);
                vpb[1] = *(const uint4*)(vg + 3072 + 8);
            }
            __syncthreads();

            // ---- S = Q @ K^T (16x64 per wave), raw scores ----
            f32x4 S[4];
#pragma unroll
            for (int ct = 0; ct < 4; ++ct) {
                f32x4 s = (f32x4){0.f, 0.f, 0.f, 0.f};
                const int row = ct * 16 + l16;
                const int key = (l16 + ct) & 7;     // (pos + (pos>>4)) & 7
#pragma unroll
                for (int ks = 0; ks < 4; ++ks) {
                    short8 kf = *(const short8*)&Kb[row * 64 + ((ks * 4 + quad) ^ key) * 4];
                    s = __builtin_amdgcn_mfma_f32_16x16x32_bf16(qf[ks], kf, s, 0, 0, 0);
                }
                S[ct] = s;
            }

            // ---- causal mask (diagonal tile only) ----
            if (t == qt) {
                const int rowloc = w * 16 + quad * 4;
#pragma unroll
                for (int ct = 0; ct < 4; ++ct)
#pragma unroll
                    for (int r = 0; r < 4; ++r)
                        if (ct * 16 + l16 > rowloc + r) S[ct][r] = -1e30f;
            }

            // ---- online softmax (scale folded into exp2) ----
#pragma unroll
            for (int r = 0; r < 4; ++r) {
                float c0 = fmaxf(fmaxf(S[0][r], S[1][r]), fmaxf(S[2][r], S[3][r]));
                c0 = fmaxf(c0, __shfl_xor(c0, 1));
                c0 = fmaxf(c0, __shfl_xor(c0, 2));
                c0 = fmaxf(c0, __shfl_xor(c0, 4));
                c0 = fmaxf(c0, __shfl_xor(c0, 8));
                float mnew = fmaxf(m_r[r], c0);
                float alpha = exp2f((m_r[r] - mnew) * k2);
                m_r[r] = mnew;
                float mh = mnew * k2;
                float rs = 0.0f;
                const int prow = quad * 4 + r;
                const int pkey = (prow >> 2) ^ ((prow & 3) << 1);
#pragma unroll
                for (int ct = 0; ct < 4; ++ct) {
                    float p = exp2f(S[ct][r] * k2 - mh);
                    rs += p;
                    int chunk = ct * 2 + (l16 >> 3);
                    union { float f; unsigned u; } pu; pu.f = p;
                    Ps[w][prow * 64 + (chunk ^ pkey) * 8 + (l16 & 7)] =
                        (unsigned short)((pu.u + 0x8000u) >> 16);
                }
                rs += __shfl_xor(rs, 1);
                rs += __shfl_xor(rs, 2);
                rs += __shfl_xor(rs, 4);
                rs += __shfl_xor(rs, 8);
                l_r[r] = l_r[r] * alpha + rs;
#pragma unroll
                for (int ot = 0; ot < 8; ++ot) Oacc[ot][r] *= alpha;
            }

            // ---- O += P @ V ----
            {
                const int pkeyr = (l16 >> 2) ^ ((l16 & 3) << 1);
                short8 pf0 = *(const short8*)&Ps[w][l16 * 64 + (quad ^ pkeyr) * 8];
                short8 pf1 = *(const short8*)&Ps[w][l16 * 64 + ((4 + quad) ^ pkeyr) * 8];
#pragma unroll
                for (int ot = 0; ot < 8; ++ot) {
                    const int d = ot * 16 + l16;
                    const int vkey = (l16 + ot) & 7;    // (d + (d>>4)) & 7
                    short8 v0 = *(const short8*)&Vb[d * 32 + (quad ^ vkey) * 4];
                    Oacc[ot] = __builtin_amdgcn_mfma_f32_16x16x32_bf16(pf0, v0, Oacc[ot], 0, 0, 0);
                    short8 v1 = *(const short8*)&Vb[d * 32 + ((4 + quad) ^ vkey) * 4];
                    Oacc[ot] = __builtin_amdgcn_mfma_f32_16x16x32_bf16(pf1, v1, Oacc[ot], 0, 0, 0);
                }
            }
            // no tail barrier: next iteration writes the other buffer
        }

        // ---- epilogue: bf16 store to [B*S, 2048] ----
        float inv[4];
#pragma unroll
        for (int r = 0; r < 4; ++r) inv[r] = 1.0f / l_r[r];
        const int orow0 = q0 + w * 16 + quad * 4;
        unsigned short* ob = o + (size_t)(b * SS + orow0) * 2048 + h * 128 + l16;
#pragma unroll
        for (int r = 0; r < 4; ++r)
#pragma unroll
            for (int ot = 0; ot < 8; ++ot)
                ob[(size_t)r * 2048 + ot * 16] = (unsigned short)f2bf1(Oacc[ot][r] * inv[r]);

        __syncthreads();   // protect LDS buffers across pass boundary
    }
}

// ---------------------------------------------------------------------------
extern "C" void kernel_launch(void* const* d_in, const int* in_sizes, int n_in,
                              void* d_out, int out_size, void* d_ws, size_t ws_size,
                              hipStream_t stream)
{
    const float* x  = (const float*)d_in[0];
    const float* Wq = (const float*)d_in[1];
    const float* bq = (const float*)d_in[2];
    const float* Wk = (const float*)d_in[3];
    const float* bk = (const float*)d_in[4];
    const float* Wv = (const float*)d_in[5];
    const float* bv = (const float*)d_in[6];
    const float* Wo = (const float*)d_in[7];
    float* out = (float*)d_out;

    const int M = BB * SS;  // 4096
    char* wsb = (char*)d_ws;
    unsigned short* xb   = (unsigned short*)wsb;  wsb += (size_t)M * EE * 2;        // 16.8 MB
    unsigned short* wqkv = (unsigned short*)wsb;  wsb += (size_t)3072 * EE * 2;     // 12.6 MB
    unsigned short* wob  = (unsigned short*)wsb;  wsb += (size_t)EE * EE * 2;       //  8.4 MB
    unsigned short* qkvb = (unsigned short*)wsb;  wsb += (size_t)M * 3072 * 2;      // 25.2 MB
    unsigned short* abb  = (unsigned short*)wsb;  wsb += (size_t)M * 2048 * 2;      // 16.8 MB
    float* bqkv = (float*)wsb;

    // one fused conversion launch (x, Wq, Wk, Wv, Wo, biases)
    cvt_all_kernel<<<18435, 256, 0, stream>>>(x, Wq, Wk, Wv, Wo, bq, bk, bv,
                                              xb, wqkv, wob, bqkv);

    // fused QKV projection: [M,3072] = xb @ wqkv^T + bqkv (bf16 out)
    gemm_mfma_kernel<true><<<dim3(3072 / 128, M / 128), 256, 0, stream>>>(
        xb, wqkv, bqkv, qkvb, M, 3072, EE);

    // RoPE on q and k heads, one launch
    rope_kernel<<<M * HH + M * KVH, 64, 0, stream>>>(qkvb);

    // flash attention -> abb (bf16)
    attn_mfma_kernel<<<dim3(16, HH, BB), 256, 0, stream>>>(qkvb, abb);

    // output projection: out = abb @ wob^T (fp32 out)
    gemm_mfma_kernel<false><<<dim3(EE / 128, M / 128), 256, 0, stream>>>(
        abb, wob, nullptr, out, M, EE, 2048);
}